// Round 2
// baseline (192.869 us; speedup 1.0000x reference)
//
#include <hip/hip_runtime.h>

#define IN_DIM  128
#define OUT_DIM 64
#define DEG     32
#define NEG_SLOPE 0.01f

// ---------------------------------------------------------------------------
// Kernel 1: z = feat @ W  [n,128]x[128,64], plus per-row scalars
//   s[r] = z[r]·aw[0:64], t[r] = z[r]·aw[64:128].
// Design: lane d (0..63) owns output dim d. The whole W column-slice
// W[k][lane], k=0..127 lives in 128 VGPRs (loaded once per wave, coalesced,
// L2-resident). Feature rows go through the SCALAR path (wave-uniform base ->
// s_load): with no LDS reads in the loop, lgkmcnt tracks only SMEM, so the
// compiler can pipeline s_loads across the fully-unrolled k-loop.
// 8 rows per wave iteration; 1024 v_fmac (s,v,v operands) per iteration.
// ---------------------------------------------------------------------------
__global__ __launch_bounds__(256, 3) void cgat_fc(
    const float* __restrict__ feat,   // [n*128]
    const float* __restrict__ W,      // [128*64] row-major (k, d)
    const float* __restrict__ aw,     // [128]
    float* __restrict__ z,            // [n*64]
    float* __restrict__ s,            // [n]
    float* __restrict__ t,            // [n]
    int n)
{
    const int lane = threadIdx.x & 63;

    // W column-slice for this lane: 128 VGPRs, coalesced 256B per k.
    float wv[IN_DIM];
    #pragma unroll
    for (int k = 0; k < IN_DIM; ++k)
        wv[k] = W[k * OUT_DIM + lane];

    const float a_s = aw[lane];
    const float a_t = aw[OUT_DIM + lane];

    const int gw = blockIdx.x * 4 + (threadIdx.x >> 6);  // global wave id
    const int nw = gridDim.x * 4;
    const int ngroups = (n + 7) / 8;

    for (int g = gw; g < ngroups; g += nw) {
        const int r = __builtin_amdgcn_readfirstlane(g * 8);  // SGPR -> s_load path

        // 8 row bases (clamped for a possible tail group); all wave-uniform.
        const float* __restrict__ fb[8];
        #pragma unroll
        for (int i = 0; i < 8; ++i) {
            int ri = r + i; if (ri > n - 1) ri = n - 1;
            fb[i] = feat + (size_t)ri * IN_DIM;
        }

        float acc[8] = {0.f, 0.f, 0.f, 0.f, 0.f, 0.f, 0.f, 0.f};
        #pragma unroll
        for (int k = 0; k < IN_DIM; ++k) {
            const float w = wv[k];
            #pragma unroll
            for (int i = 0; i < 8; ++i)
                acc[i] = fmaf(fb[i][k], w, acc[i]);   // v_fmac acc, s_f, v_w
        }

        #pragma unroll
        for (int i = 0; i < 8; ++i) {
            int ri = r + i; if (ri > n - 1) ri = n - 1;
            z[(size_t)ri * OUT_DIM + lane] = acc[i];
            float sv = acc[i] * a_s;
            float tv = acc[i] * a_t;
            #pragma unroll
            for (int off = 32; off > 0; off >>= 1) {
                sv += __shfl_xor(sv, off, 64);
                tv += __shfl_xor(tv, off, 64);
            }
            if (lane == 0) { s[ri] = sv; t[ri] = tv; }
        }
    }
}

// ---------------------------------------------------------------------------
// Kernel 2: per node n (one wave each):
//   e_j     = leaky_relu(s[idx[n,j]] + t[n]),            j = 0..31
//   alpha_j = sum_k max(e_j - e_k, 0)
//   h[n,d]  = sum_j alpha_j * z[idx[n,j]][d],            lane d = 0..63
// readlane (compile-time lane index) puts per-j scalars in SGPRs, so the
// z-row gather is `global_load_dword v, v_off, s[base]` (coalesced 256B).
// 4-way split accumulators break the serial FMA/max dependency chains.
// ---------------------------------------------------------------------------
__global__ __launch_bounds__(256) void cgat_gather(
    const int*   __restrict__ idx,    // [n*32]
    const float* __restrict__ z,      // [n*64]
    const float* __restrict__ s,      // [n]
    const float* __restrict__ t,      // [n]
    float* __restrict__ h,            // [n*64]
    int n)
{
    const int lane = threadIdx.x & 63;
    int node = blockIdx.x * 4 + (threadIdx.x >> 6);
    if (node >= n) return;
    node = __builtin_amdgcn_readfirstlane(node);

    const int   j  = lane & 31;                       // upper 32 lanes duplicate
    const int   ij = idx[(size_t)node * DEG + j];     // one 128B segment per wave
    const float tn = t[node];

    float e = s[ij] + tn;                             // random 4B gather (L2-hot table)
    e = (e >= 0.f) ? e : NEG_SLOPE * e;

    // alpha_j = sum_k max(e_j - e_k, 0), 4 partial chains
    float al0 = 0.f, al1 = 0.f, al2 = 0.f, al3 = 0.f;
    #pragma unroll
    for (int k = 0; k < DEG; k += 4) {
        const float e0 = __int_as_float(__builtin_amdgcn_readlane(__float_as_int(e), k + 0));
        const float e1 = __int_as_float(__builtin_amdgcn_readlane(__float_as_int(e), k + 1));
        const float e2 = __int_as_float(__builtin_amdgcn_readlane(__float_as_int(e), k + 2));
        const float e3 = __int_as_float(__builtin_amdgcn_readlane(__float_as_int(e), k + 3));
        al0 += fmaxf(e - e0, 0.f);
        al1 += fmaxf(e - e1, 0.f);
        al2 += fmaxf(e - e2, 0.f);
        al3 += fmaxf(e - e3, 0.f);
    }
    const float alpha = (al0 + al1) + (al2 + al3);

    // h[node, lane] = sum_j alpha_j * z[idx_j, lane], 4 partial chains
    float h0 = 0.f, h1 = 0.f, h2 = 0.f, h3 = 0.f;
    #pragma unroll
    for (int k = 0; k < DEG; k += 4) {
        const float a0 = __int_as_float(__builtin_amdgcn_readlane(__float_as_int(alpha), k + 0));
        const float a1 = __int_as_float(__builtin_amdgcn_readlane(__float_as_int(alpha), k + 1));
        const float a2 = __int_as_float(__builtin_amdgcn_readlane(__float_as_int(alpha), k + 2));
        const float a3 = __int_as_float(__builtin_amdgcn_readlane(__float_as_int(alpha), k + 3));
        const int   i0 = __builtin_amdgcn_readlane(ij, k + 0);
        const int   i1 = __builtin_amdgcn_readlane(ij, k + 1);
        const int   i2 = __builtin_amdgcn_readlane(ij, k + 2);
        const int   i3 = __builtin_amdgcn_readlane(ij, k + 3);
        h0 = fmaf(a0, z[(size_t)i0 * OUT_DIM + lane], h0);
        h1 = fmaf(a1, z[(size_t)i1 * OUT_DIM + lane], h1);
        h2 = fmaf(a2, z[(size_t)i2 * OUT_DIM + lane], h2);
        h3 = fmaf(a3, z[(size_t)i3 * OUT_DIM + lane], h3);
    }
    h[(size_t)node * OUT_DIM + lane] = (h0 + h1) + (h2 + h3);
}

// ---------------------------------------------------------------------------
extern "C" void kernel_launch(void* const* d_in, const int* in_sizes, int n_in,
                              void* d_out, int out_size, void* d_ws, size_t ws_size,
                              hipStream_t stream)
{
    const float* feat = (const float*)d_in[0];   // [N,128] f32
    const int*   idx  = (const int*)  d_in[1];   // [N,32]  i32
    const float* W    = (const float*)d_in[2];   // [128,64] f32
    const float* aw   = (const float*)d_in[3];   // [128,1] f32
    float*       h    = (float*)d_out;           // [N,64] f32

    const int n = in_sizes[0] / IN_DIM;

    // workspace: z [n*64] f32, s [n] f32, t [n] f32 (fully rewritten each launch)
    float* z = (float*)d_ws;
    float* s = z + (size_t)n * OUT_DIM;
    float* t = s + n;

    cgat_fc<<<768, 256, 0, stream>>>(feat, W, aw, z, s, t, n);

    const int blocks = (n + 3) / 4;   // one wave per node, 4 waves/block
    cgat_gather<<<blocks, 256, 0, stream>>>(idx, z, s, t, h, n);
}

// Round 3
// 165.793 us; speedup vs baseline: 1.1633x; 1.1633x over previous
//
#include <hip/hip_runtime.h>

#define IN_DIM  128
#define OUT_DIM 64
#define DEG     32
#define NEG_SLOPE 0.01f
#define WT_PAD  132   // floats per row of transposed-W LDS tile: 528B = 16B-aligned,
                      // bank = (4d+k)%32 -> 8 lanes/bank-group = ds_read_b128 floor

// ---------------------------------------------------------------------------
// Kernel 1: z = feat @ W  [n,128]x[128,64]  + s[r]=z[r]·aw[:64], t[r]=z[r]·aw[64:]
// Lane d (0..63) owns output dim d. Per wave: ONE 4-row job (exact grid).
//  - feat 4-row tile (2KB) -> 2 coalesced float4 loads/lane (vmcnt, counted)
//  - broadcast feat[row][k] via v_readlane (imm lane) -> SGPR operand of v_fmac
//  - W transposed in LDS: Wt[d][k], ds_read_b128 (in-order lgkm, counted)
// NO SMEM in the hot path => no out-of-order lgkmcnt(0) serialization.
// ---------------------------------------------------------------------------
__global__ __launch_bounds__(256) void cgat_fc(
    const float* __restrict__ feat,   // [n*128]
    const float* __restrict__ W,      // [128*64] row-major (k, d)
    const float* __restrict__ aw,     // [128]
    float* __restrict__ z,            // [n*64]
    float* __restrict__ s,            // [n]
    float* __restrict__ t,            // [n]
    int n)
{
    __shared__ float Wt[OUT_DIM * WT_PAD];   // 33.8 KB
    // stage + transpose W: i = k*64 + d (coalesced global read)
    for (int i = threadIdx.x; i < IN_DIM * OUT_DIM; i += 256) {
        const int k = i >> 6, d = i & 63;
        Wt[d * WT_PAD + k] = W[i];
    }
    __syncthreads();

    const int lane = threadIdx.x & 63;
    const float a_s = aw[lane];
    const float a_t = aw[OUT_DIM + lane];

    int r0 = (blockIdx.x * 4 + (threadIdx.x >> 6)) * 4;   // 4 rows per wave
    if (r0 >= n) return;
    if (r0 + 4 > n) r0 = (n >= 4) ? (n - 4) : 0;          // overlap-tail (idempotent)
    r0 = __builtin_amdgcn_readfirstlane(r0);

    // 4 feat rows = 512 floats: lane holds elems [lane*8, lane*8+8)
    const float4* fb = (const float4*)(feat + (size_t)r0 * IN_DIM);
    const float4 fA = fb[lane * 2 + 0];
    const float4 fB = fb[lane * 2 + 1];
    const int fAi[4] = {__float_as_int(fA.x), __float_as_int(fA.y),
                        __float_as_int(fA.z), __float_as_int(fA.w)};
    const int fBi[4] = {__float_as_int(fB.x), __float_as_int(fB.y),
                        __float_as_int(fB.z), __float_as_int(fB.w)};

    float acc[4] = {0.f, 0.f, 0.f, 0.f};

    #pragma unroll
    for (int kc = 0; kc < 4; ++kc) {               // 4 chunks of 32 k
        // W chunk: Wt[lane][kc*32 .. +32) = 8 x ds_read_b128
        float4 w[8];
        #pragma unroll
        for (int u = 0; u < 8; ++u)
            w[u] = *(const float4*)&Wt[lane * WT_PAD + kc * 32 + u * 4];

        #pragma unroll
        for (int r = 0; r < 4; ++r) {
            #pragma unroll
            for (int kk = 0; kk < 32; ++kk) {
                const int k   = kc * 32 + kk;
                const int src = r * 16 + (k >> 3);   // owning lane (imm)
                const int sub = k & 7;               // element in that lane (imm)
                const int fi  = (sub < 4) ? fAi[sub] : fBi[sub - 4];
                const float f = __int_as_float(__builtin_amdgcn_readlane(fi, src));
                acc[r] = fmaf(f, w[kk >> 2][kk & 3], acc[r]);
            }
        }
    }

    #pragma unroll
    for (int r = 0; r < 4; ++r) {
        z[(size_t)(r0 + r) * OUT_DIM + lane] = acc[r];
        float sv = acc[r] * a_s;
        float tv = acc[r] * a_t;
        #pragma unroll
        for (int off = 32; off > 0; off >>= 1) {
            sv += __shfl_xor(sv, off, 64);
            tv += __shfl_xor(tv, off, 64);
        }
        if (lane == 0) { s[r0 + r] = sv; t[r0 + r] = tv; }
    }
}

// ---------------------------------------------------------------------------
// Kernel 2: per node n (one wave each):
//   e_j     = leaky_relu(s[idx[n,j]] + t[n]),            j = 0..31
//   alpha_j = sum_k max(e_j - e_k, 0)
//   h[n,d]  = sum_j alpha_j * z[idx[n,j]][d],            lane d = 0..63
// All 32 z-row gathers preloaded into a register array (32 independent
// coalesced 256B loads in flight) before the fma chains.
// ---------------------------------------------------------------------------
__global__ __launch_bounds__(256) void cgat_gather(
    const int*   __restrict__ idx,    // [n*32]
    const float* __restrict__ z,      // [n*64]
    const float* __restrict__ s,      // [n]
    const float* __restrict__ t,      // [n]
    float* __restrict__ h,            // [n*64]
    int n)
{
    const int lane = threadIdx.x & 63;
    int node = blockIdx.x * 4 + (threadIdx.x >> 6);
    if (node >= n) return;
    node = __builtin_amdgcn_readfirstlane(node);

    const int   j  = lane & 31;                       // upper 32 lanes duplicate
    const int   ij = idx[(size_t)node * DEG + j];     // one 128B segment per wave
    const float tn = t[node];

    // preload all 32 z rows (lane owns dim): 32 independent 256B gathers
    float zr[DEG];
    #pragma unroll
    for (int k = 0; k < DEG; ++k) {
        const int ik = __builtin_amdgcn_readlane(ij, k);
        zr[k] = z[(size_t)ik * OUT_DIM + lane];
    }

    float e = s[ij] + tn;                             // random 4B gather (L2-hot table)
    e = (e >= 0.f) ? e : NEG_SLOPE * e;

    // alpha_j = sum_k max(e_j - e_k, 0), 4 partial chains
    float al0 = 0.f, al1 = 0.f, al2 = 0.f, al3 = 0.f;
    #pragma unroll
    for (int k = 0; k < DEG; k += 4) {
        const float e0 = __int_as_float(__builtin_amdgcn_readlane(__float_as_int(e), k + 0));
        const float e1 = __int_as_float(__builtin_amdgcn_readlane(__float_as_int(e), k + 1));
        const float e2 = __int_as_float(__builtin_amdgcn_readlane(__float_as_int(e), k + 2));
        const float e3 = __int_as_float(__builtin_amdgcn_readlane(__float_as_int(e), k + 3));
        al0 += fmaxf(e - e0, 0.f);
        al1 += fmaxf(e - e1, 0.f);
        al2 += fmaxf(e - e2, 0.f);
        al3 += fmaxf(e - e3, 0.f);
    }
    const float alpha = (al0 + al1) + (al2 + al3);

    // h[node, lane] = sum_j alpha_j * zr[j], 4 partial chains
    float h0 = 0.f, h1 = 0.f, h2 = 0.f, h3 = 0.f;
    #pragma unroll
    for (int k = 0; k < DEG; k += 4) {
        const float a0 = __int_as_float(__builtin_amdgcn_readlane(__float_as_int(alpha), k + 0));
        const float a1 = __int_as_float(__builtin_amdgcn_readlane(__float_as_int(alpha), k + 1));
        const float a2 = __int_as_float(__builtin_amdgcn_readlane(__float_as_int(alpha), k + 2));
        const float a3 = __int_as_float(__builtin_amdgcn_readlane(__float_as_int(alpha), k + 3));
        h0 = fmaf(a0, zr[k + 0], h0);
        h1 = fmaf(a1, zr[k + 1], h1);
        h2 = fmaf(a2, zr[k + 2], h2);
        h3 = fmaf(a3, zr[k + 3], h3);
    }
    h[(size_t)node * OUT_DIM + lane] = (h0 + h1) + (h2 + h3);
}

// ---------------------------------------------------------------------------
extern "C" void kernel_launch(void* const* d_in, const int* in_sizes, int n_in,
                              void* d_out, int out_size, void* d_ws, size_t ws_size,
                              hipStream_t stream)
{
    const float* feat = (const float*)d_in[0];   // [N,128] f32
    const int*   idx  = (const int*)  d_in[1];   // [N,32]  i32
    const float* W    = (const float*)d_in[2];   // [128,64] f32
    const float* aw   = (const float*)d_in[3];   // [128,1] f32
    float*       h    = (float*)d_out;           // [N,64] f32

    const int n = in_sizes[0] / IN_DIM;

    // workspace: z [n*64] f32, s [n] f32, t [n] f32 (fully rewritten each launch)
    float* z = (float*)d_ws;
    float* s = z + (size_t)n * OUT_DIM;
    float* t = s + n;

    const int fc_blocks = (n + 15) / 16;         // 4 waves/block, 4 rows/wave
    cgat_fc<<<fc_blocks, 256, 0, stream>>>(feat, W, aw, z, s, t, n);

    const int ga_blocks = (n + 3) / 4;           // one wave per node
    cgat_gather<<<ga_blocks, 256, 0, stream>>>(idx, z, s, t, h, n);
}

// Round 4
// 134.597 us; speedup vs baseline: 1.4329x; 1.2318x over previous
//
#include <hip/hip_runtime.h>

#define IN_DIM  128
#define OUT_DIM 64
#define DEG     32
#define NEG_SLOPE 0.01f

typedef __attribute__((ext_vector_type(8))) short  short8;   // 8 bf16 (4 VGPRs)
typedef __attribute__((ext_vector_type(4))) float  f32x4;    // MFMA acc

// f32 -> bf16 bits, round-to-nearest-even
__device__ __forceinline__ unsigned short f2bf(float x) {
    unsigned u = __float_as_uint(x);
    unsigned r = u + 0x7FFFu + ((u >> 16) & 1u);
    return (unsigned short)(r >> 16);
}
__device__ __forceinline__ float bf2f(unsigned short b) {
    return __uint_as_float(((unsigned)b) << 16);
}

// ---------------------------------------------------------------------------
// Kernel 1 (MFMA): z = feat @ W via split-bf16 (hi/lo), plus
//   s[r]=z[r]·aw[:64], t[r]=z[r]·aw[64:].
// Per wave job = 16 rows x 64 dims, K=128.
//   A-slot(lane,j) = feat[r0 + (lane&15)][ kt*32 + 8*(lane>>4) + j ]
//   B-slot(lane,j) = W  [ kt*32 + 8*(lane>>4) + j ][ nt*16 + (lane&15) ]
// Same k-bijection on both operands => correct for any HW k-slot ordering.
// D (measured m89): col = lane&15, row = 4*(lane>>4) + reg.
// B frags (hi+lo, 128 VGPRs) built once per wave, reused across jobs.
// ---------------------------------------------------------------------------
__global__ __launch_bounds__(256) void cgat_fc(
    const float* __restrict__ feat,   // [n*128]
    const float* __restrict__ W,      // [128*64] row-major (k, d)
    const float* __restrict__ aw,     // [128]
    float* __restrict__ z,            // [n*64]
    float* __restrict__ s,            // [n]
    float* __restrict__ t,            // [n]
    int n)
{
    const int lane = threadIdx.x & 63;
    const int hi   = lane >> 4;
    const int lo   = lane & 15;

    // ---- B fragments: W split into bf16 hi/lo, once per wave ----
    short8 Bh[4][4], Bl[4][4];
    #pragma unroll
    for (int kt = 0; kt < 4; ++kt) {
        #pragma unroll
        for (int nt = 0; nt < 4; ++nt) {
            #pragma unroll
            for (int j = 0; j < 8; ++j) {
                const float w = W[(kt * 32 + hi * 8 + j) * OUT_DIM + nt * 16 + lo];
                const unsigned short h = f2bf(w);
                Bh[kt][nt][j] = (short)h;
                Bl[kt][nt][j] = (short)f2bf(w - bf2f(h));
            }
        }
    }

    float aw_s[4], aw_t[4];
    #pragma unroll
    for (int nt = 0; nt < 4; ++nt) {
        aw_s[nt] = aw[nt * 16 + lo];
        aw_t[nt] = aw[OUT_DIM + nt * 16 + lo];
    }

    const int wave   = blockIdx.x * 4 + (threadIdx.x >> 6);
    const int nwaves = gridDim.x * 4;
    const int njobs  = (n + 15) >> 4;

    for (int job = wave; job < njobs; job += nwaves) {
        int r0 = job << 4;
        if (r0 + 16 > n) r0 = n - 16;              // overlap-tail, idempotent
        const float* frow = feat + (size_t)(r0 + lo) * IN_DIM + hi * 8;

        f32x4 acc[4] = {{0,0,0,0},{0,0,0,0},{0,0,0,0},{0,0,0,0}};

        #pragma unroll
        for (int kt = 0; kt < 4; ++kt) {
            const float4 a0 = *(const float4*)(frow + kt * 32);
            const float4 a1 = *(const float4*)(frow + kt * 32 + 4);
            const float av[8] = {a0.x, a0.y, a0.z, a0.w, a1.x, a1.y, a1.z, a1.w};
            short8 Ah, Al;
            #pragma unroll
            for (int j = 0; j < 8; ++j) {
                const unsigned short h = f2bf(av[j]);
                Ah[j] = (short)h;
                Al[j] = (short)f2bf(av[j] - bf2f(h));
            }
            #pragma unroll
            for (int nt = 0; nt < 4; ++nt) {
                acc[nt] = __builtin_amdgcn_mfma_f32_16x16x32_bf16(Ah, Bh[kt][nt], acc[nt], 0, 0, 0);
                acc[nt] = __builtin_amdgcn_mfma_f32_16x16x32_bf16(Ah, Bl[kt][nt], acc[nt], 0, 0, 0);
                acc[nt] = __builtin_amdgcn_mfma_f32_16x16x32_bf16(Al, Bh[kt][nt], acc[nt], 0, 0, 0);
            }
        }

        // epilogue: z store + s,t dot-reduce (16-lane groups)
        #pragma unroll
        for (int reg = 0; reg < 4; ++reg) {
            const int row = r0 + 4 * hi + reg;
            float sv = 0.f, tv = 0.f;
            #pragma unroll
            for (int nt = 0; nt < 4; ++nt) {
                const float v = acc[nt][reg];
                z[(size_t)row * OUT_DIM + nt * 16 + lo] = v;
                sv = fmaf(v, aw_s[nt], sv);
                tv = fmaf(v, aw_t[nt], tv);
            }
            #pragma unroll
            for (int off = 8; off > 0; off >>= 1) {
                sv += __shfl_xor(sv, off, 64);
                tv += __shfl_xor(tv, off, 64);
            }
            if (lo == 0) { s[row] = sv; t[row] = tv; }
        }
    }
}

// ---------------------------------------------------------------------------
// Kernel 2 (round-2 version — best measured): per node (one wave each):
//   e_j     = leaky_relu(s[idx[n,j]] + t[n])
//   alpha_j = sum_k max(e_j - e_k, 0)
//   h[n,d]  = sum_j alpha_j * z[idx[n,j]][d]     (lane d = 0..63)
// readlane (imm lane) -> per-j scalars in SGPRs; z-row gather is a coalesced
// 256B load; 4-way split accumulators break serial chains.
// ---------------------------------------------------------------------------
__global__ __launch_bounds__(256) void cgat_gather(
    const int*   __restrict__ idx,    // [n*32]
    const float* __restrict__ z,      // [n*64]
    const float* __restrict__ s,      // [n]
    const float* __restrict__ t,      // [n]
    float* __restrict__ h,            // [n*64]
    int n)
{
    const int lane = threadIdx.x & 63;
    int node = blockIdx.x * 4 + (threadIdx.x >> 6);
    if (node >= n) return;
    node = __builtin_amdgcn_readfirstlane(node);

    const int   j  = lane & 31;                       // upper 32 lanes duplicate
    const int   ij = idx[(size_t)node * DEG + j];     // one 128B segment per wave
    const float tn = t[node];

    float e = s[ij] + tn;                             // random 4B gather (L2-hot)
    e = (e >= 0.f) ? e : NEG_SLOPE * e;

    float al0 = 0.f, al1 = 0.f, al2 = 0.f, al3 = 0.f;
    #pragma unroll
    for (int k = 0; k < DEG; k += 4) {
        const float e0 = __int_as_float(__builtin_amdgcn_readlane(__float_as_int(e), k + 0));
        const float e1 = __int_as_float(__builtin_amdgcn_readlane(__float_as_int(e), k + 1));
        const float e2 = __int_as_float(__builtin_amdgcn_readlane(__float_as_int(e), k + 2));
        const float e3 = __int_as_float(__builtin_amdgcn_readlane(__float_as_int(e), k + 3));
        al0 += fmaxf(e - e0, 0.f);
        al1 += fmaxf(e - e1, 0.f);
        al2 += fmaxf(e - e2, 0.f);
        al3 += fmaxf(e - e3, 0.f);
    }
    const float alpha = (al0 + al1) + (al2 + al3);

    float h0 = 0.f, h1 = 0.f, h2 = 0.f, h3 = 0.f;
    #pragma unroll
    for (int k = 0; k < DEG; k += 4) {
        const float a0 = __int_as_float(__builtin_amdgcn_readlane(__float_as_int(alpha), k + 0));
        const float a1 = __int_as_float(__builtin_amdgcn_readlane(__float_as_int(alpha), k + 1));
        const float a2 = __int_as_float(__builtin_amdgcn_readlane(__float_as_int(alpha), k + 2));
        const float a3 = __int_as_float(__builtin_amdgcn_readlane(__float_as_int(alpha), k + 3));
        const int   i0 = __builtin_amdgcn_readlane(ij, k + 0);
        const int   i1 = __builtin_amdgcn_readlane(ij, k + 1);
        const int   i2 = __builtin_amdgcn_readlane(ij, k + 2);
        const int   i3 = __builtin_amdgcn_readlane(ij, k + 3);
        h0 = fmaf(a0, z[(size_t)i0 * OUT_DIM + lane], h0);
        h1 = fmaf(a1, z[(size_t)i1 * OUT_DIM + lane], h1);
        h2 = fmaf(a2, z[(size_t)i2 * OUT_DIM + lane], h2);
        h3 = fmaf(a3, z[(size_t)i3 * OUT_DIM + lane], h3);
    }
    h[(size_t)node * OUT_DIM + lane] = (h0 + h1) + (h2 + h3);
}

// ---------------------------------------------------------------------------
extern "C" void kernel_launch(void* const* d_in, const int* in_sizes, int n_in,
                              void* d_out, int out_size, void* d_ws, size_t ws_size,
                              hipStream_t stream)
{
    const float* feat = (const float*)d_in[0];   // [N,128] f32
    const int*   idx  = (const int*)  d_in[1];   // [N,32]  i32
    const float* W    = (const float*)d_in[2];   // [128,64] f32
    const float* aw   = (const float*)d_in[3];   // [128,1] f32
    float*       h    = (float*)d_out;           // [N,64] f32

    const int n = in_sizes[0] / IN_DIM;

    // workspace: z [n*64] f32, s [n] f32, t [n] f32 (fully rewritten each launch)
    float* z = (float*)d_ws;
    float* s = z + (size_t)n * OUT_DIM;
    float* t = s + n;

    cgat_fc<<<512, 256, 0, stream>>>(feat, W, aw, z, s, t, n);   // 2048 waves, grid-stride

    const int ga_blocks = (n + 3) / 4;           // one wave per node
    cgat_gather<<<ga_blocks, 256, 0, stream>>>(idx, z, s, t, h, n);
}

// Round 5
// 120.123 us; speedup vs baseline: 1.6056x; 1.1205x over previous
//
#include <hip/hip_runtime.h>

#define IN_DIM  128
#define OUT_DIM 64
#define DEG     32
#define NEG_SLOPE 0.01f

typedef __attribute__((ext_vector_type(8))) short  short8;   // 8 bf16 (4 VGPRs)
typedef __attribute__((ext_vector_type(4))) float  f32x4;    // MFMA acc

// f32 -> bf16 bits, round-to-nearest-even
__device__ __forceinline__ unsigned short f2bf(float x) {
    unsigned u = __float_as_uint(x);
    unsigned r = u + 0x7FFFu + ((u >> 16) & 1u);
    return (unsigned short)(r >> 16);
}
__device__ __forceinline__ float bf2f(unsigned short b) {
    return __uint_as_float(((unsigned)b) << 16);
}

// ---------------------------------------------------------------------------
// Kernel 1 (MFMA): z = feat @ W via split-bf16 (hi/lo), plus
//   s[r]=z[r]·aw[:64], t[r]=z[r]·aw[64:].
// z mailbox stored as bf16 (zb) — halves gather-side cache traffic.
// Per wave job = 16 rows x 64 dims, K=128.
//   A-slot(lane,j) = feat[r0 + (lane&15)][ kt*32 + 8*(lane>>4) + j ]
//   B-slot(lane,j) = W  [ kt*32 + 8*(lane>>4) + j ][ nt*16 + (lane&15) ]
// Same k-bijection on both operands => correct for any HW k-slot ordering.
// D (measured m89): col = lane&15, row = 4*(lane>>4) + reg.
// ---------------------------------------------------------------------------
__global__ __launch_bounds__(256) void cgat_fc(
    const float* __restrict__ feat,   // [n*128]
    const float* __restrict__ W,      // [128*64] row-major (k, d)
    const float* __restrict__ aw,     // [128]
    unsigned short* __restrict__ zb,  // [n*64] bf16 mailbox
    float* __restrict__ s,            // [n]
    float* __restrict__ t,            // [n]
    int n)
{
    const int lane = threadIdx.x & 63;
    const int hi   = lane >> 4;
    const int lo   = lane & 15;

    // ---- B fragments: W split into bf16 hi/lo, once per wave ----
    short8 Bh[4][4], Bl[4][4];
    #pragma unroll
    for (int kt = 0; kt < 4; ++kt) {
        #pragma unroll
        for (int nt = 0; nt < 4; ++nt) {
            #pragma unroll
            for (int j = 0; j < 8; ++j) {
                const float w = W[(kt * 32 + hi * 8 + j) * OUT_DIM + nt * 16 + lo];
                const unsigned short h = f2bf(w);
                Bh[kt][nt][j] = (short)h;
                Bl[kt][nt][j] = (short)f2bf(w - bf2f(h));
            }
        }
    }

    float aw_s[4], aw_t[4];
    #pragma unroll
    for (int nt = 0; nt < 4; ++nt) {
        aw_s[nt] = aw[nt * 16 + lo];
        aw_t[nt] = aw[OUT_DIM + nt * 16 + lo];
    }

    const int wave   = blockIdx.x * 4 + (threadIdx.x >> 6);
    const int nwaves = gridDim.x * 4;
    const int njobs  = (n + 15) >> 4;

    for (int job = wave; job < njobs; job += nwaves) {
        int r0 = job << 4;
        if (r0 + 16 > n) r0 = (n >= 16) ? (n - 16) : 0;   // overlap-tail, idempotent
        const float* frow = feat + (size_t)(r0 + lo) * IN_DIM + hi * 8;

        f32x4 acc[4] = {{0,0,0,0},{0,0,0,0},{0,0,0,0},{0,0,0,0}};

        #pragma unroll
        for (int kt = 0; kt < 4; ++kt) {
            const float4 a0 = *(const float4*)(frow + kt * 32);
            const float4 a1 = *(const float4*)(frow + kt * 32 + 4);
            const float av[8] = {a0.x, a0.y, a0.z, a0.w, a1.x, a1.y, a1.z, a1.w};
            short8 Ah, Al;
            #pragma unroll
            for (int j = 0; j < 8; ++j) {
                const unsigned short h = f2bf(av[j]);
                Ah[j] = (short)h;
                Al[j] = (short)f2bf(av[j] - bf2f(h));
            }
            #pragma unroll
            for (int nt = 0; nt < 4; ++nt) {
                acc[nt] = __builtin_amdgcn_mfma_f32_16x16x32_bf16(Ah, Bh[kt][nt], acc[nt], 0, 0, 0);
                acc[nt] = __builtin_amdgcn_mfma_f32_16x16x32_bf16(Ah, Bl[kt][nt], acc[nt], 0, 0, 0);
                acc[nt] = __builtin_amdgcn_mfma_f32_16x16x32_bf16(Al, Bh[kt][nt], acc[nt], 0, 0, 0);
            }
        }

        // epilogue: zb (bf16) store + s,t dot-reduce (16-lane groups)
        #pragma unroll
        for (int reg = 0; reg < 4; ++reg) {
            const int row = r0 + 4 * hi + reg;
            float sv = 0.f, tv = 0.f;
            #pragma unroll
            for (int nt = 0; nt < 4; ++nt) {
                const float v = acc[nt][reg];
                zb[(size_t)row * OUT_DIM + nt * 16 + lo] = f2bf(v);
                sv = fmaf(v, aw_s[nt], sv);
                tv = fmaf(v, aw_t[nt], tv);
            }
            #pragma unroll
            for (int off = 8; off > 0; off >>= 1) {
                sv += __shfl_xor(sv, off, 64);
                tv += __shfl_xor(tv, off, 64);
            }
            if (lo == 0) { s[row] = sv; t[row] = tv; }
        }
    }
}

// ---------------------------------------------------------------------------
// Kernel 2: per node (one wave each):
//   e_j     = leaky_relu(s[idx[n,j]] + t[n])        (lanes 0..31 only ->
//                                                    halves random-line count)
//   alpha_j = sum_k max(e_j - e_k, 0)
//   h[n,d]  = sum_j alpha_j * bf2f(zb[idx_j][d])    (lane d = 0..63, 128B rows)
// readlane ignores exec -> broadcasts from lanes 0..31 stay valid.
// ---------------------------------------------------------------------------
__global__ __launch_bounds__(256) void cgat_gather(
    const int*   __restrict__ idx,    // [n*32]
    const unsigned short* __restrict__ zb,  // [n*64] bf16
    const float* __restrict__ s,      // [n]
    const float* __restrict__ t,      // [n]
    float* __restrict__ h,            // [n*64]
    int n)
{
    const int lane = threadIdx.x & 63;
    int node = blockIdx.x * 4 + (threadIdx.x >> 6);
    if (node >= n) return;
    node = __builtin_amdgcn_readfirstlane(node);

    const float tn = t[node];

    // e on lanes 0..31 only: 32 random 4B lines instead of 64
    int   ij = 0;
    float e  = 0.f;
    if (lane < DEG) {
        ij = idx[(size_t)node * DEG + lane];      // one 128B segment
        e  = s[ij] + tn;                          // random 4B gather (L2-hot)
        e  = (e >= 0.f) ? e : NEG_SLOPE * e;
    }

    float al0 = 0.f, al1 = 0.f, al2 = 0.f, al3 = 0.f;
    #pragma unroll
    for (int k = 0; k < DEG; k += 4) {
        const float e0 = __int_as_float(__builtin_amdgcn_readlane(__float_as_int(e), k + 0));
        const float e1 = __int_as_float(__builtin_amdgcn_readlane(__float_as_int(e), k + 1));
        const float e2 = __int_as_float(__builtin_amdgcn_readlane(__float_as_int(e), k + 2));
        const float e3 = __int_as_float(__builtin_amdgcn_readlane(__float_as_int(e), k + 3));
        al0 += fmaxf(e - e0, 0.f);
        al1 += fmaxf(e - e1, 0.f);
        al2 += fmaxf(e - e2, 0.f);
        al3 += fmaxf(e - e3, 0.f);
    }
    const float alpha = (al0 + al1) + (al2 + al3);   // valid in lanes 0..31

    float h0 = 0.f, h1 = 0.f, h2 = 0.f, h3 = 0.f;
    #pragma unroll
    for (int k = 0; k < DEG; k += 4) {
        const float a0 = __int_as_float(__builtin_amdgcn_readlane(__float_as_int(alpha), k + 0));
        const float a1 = __int_as_float(__builtin_amdgcn_readlane(__float_as_int(alpha), k + 1));
        const float a2 = __int_as_float(__builtin_amdgcn_readlane(__float_as_int(alpha), k + 2));
        const float a3 = __int_as_float(__builtin_amdgcn_readlane(__float_as_int(alpha), k + 3));
        const int   i0 = __builtin_amdgcn_readlane(ij, k + 0);
        const int   i1 = __builtin_amdgcn_readlane(ij, k + 1);
        const int   i2 = __builtin_amdgcn_readlane(ij, k + 2);
        const int   i3 = __builtin_amdgcn_readlane(ij, k + 3);
        h0 = fmaf(a0, bf2f(zb[(size_t)i0 * OUT_DIM + lane]), h0);  // 128B coalesced row
        h1 = fmaf(a1, bf2f(zb[(size_t)i1 * OUT_DIM + lane]), h1);
        h2 = fmaf(a2, bf2f(zb[(size_t)i2 * OUT_DIM + lane]), h2);
        h3 = fmaf(a3, bf2f(zb[(size_t)i3 * OUT_DIM + lane]), h3);
    }
    h[(size_t)node * OUT_DIM + lane] = (h0 + h1) + (h2 + h3);
}

// ---------------------------------------------------------------------------
extern "C" void kernel_launch(void* const* d_in, const int* in_sizes, int n_in,
                              void* d_out, int out_size, void* d_ws, size_t ws_size,
                              hipStream_t stream)
{
    const float* feat = (const float*)d_in[0];   // [N,128] f32
    const int*   idx  = (const int*)  d_in[1];   // [N,32]  i32
    const float* W    = (const float*)d_in[2];   // [128,64] f32
    const float* aw   = (const float*)d_in[3];   // [128,1] f32
    float*       h    = (float*)d_out;           // [N,64] f32

    const int n = in_sizes[0] / IN_DIM;

    // workspace: s [n] f32, t [n] f32, zb [n*64] bf16 (all fully rewritten)
    float* s = (float*)d_ws;
    float* t = s + n;
    unsigned short* zb = (unsigned short*)(t + n);

    cgat_fc<<<512, 256, 0, stream>>>(feat, W, aw, zb, s, t, n);   // grid-stride

    const int ga_blocks = (n + 3) / 4;           // one wave per node
    cgat_gather<<<ga_blocks, 256, 0, stream>>>(idx, zb, s, t, h, n);
}

// Round 6
// 118.623 us; speedup vs baseline: 1.6259x; 1.0126x over previous
//
#include <hip/hip_runtime.h>

#define IN_DIM  128
#define OUT_DIM 64
#define DEG     32
#define NEG_SLOPE 0.01f

typedef __attribute__((ext_vector_type(8))) short  short8;   // 8 bf16 (4 VGPRs)
typedef __attribute__((ext_vector_type(4))) float  f32x4;    // MFMA acc

// f32 -> bf16 bits, round-to-nearest-even
__device__ __forceinline__ unsigned short f2bf(float x) {
    unsigned u = __float_as_uint(x);
    unsigned r = u + 0x7FFFu + ((u >> 16) & 1u);
    return (unsigned short)(r >> 16);
}
__device__ __forceinline__ float bf2f(unsigned short b) {
    return __uint_as_float(((unsigned)b) << 16);
}

// ---------------------------------------------------------------------------
// Kernel 1 (MFMA, unchanged from round 5 — measured ~7us): z = feat @ W via
// split-bf16 (hi/lo); z mailbox stored bf16; s[r]=z[r]·aw[:64], t[r]=z[r]·aw[64:].
// Per wave job = 16 rows x 64 dims, K=128.
//   A-slot(lane,j) = feat[r0 + (lane&15)][ kt*32 + 8*(lane>>4) + j ]
//   B-slot(lane,j) = W  [ kt*32 + 8*(lane>>4) + j ][ nt*16 + (lane&15) ]
// Same k-bijection on both operands => correct for any HW k-slot ordering.
// D (measured m89): col = lane&15, row = 4*(lane>>4) + reg.
// ---------------------------------------------------------------------------
__global__ __launch_bounds__(256) void cgat_fc(
    const float* __restrict__ feat,   // [n*128]
    const float* __restrict__ W,      // [128*64] row-major (k, d)
    const float* __restrict__ aw,     // [128]
    unsigned short* __restrict__ zb,  // [n*64] bf16 mailbox
    float* __restrict__ s,            // [n]
    float* __restrict__ t,            // [n]
    int n)
{
    const int lane = threadIdx.x & 63;
    const int hi   = lane >> 4;
    const int lo   = lane & 15;

    short8 Bh[4][4], Bl[4][4];
    #pragma unroll
    for (int kt = 0; kt < 4; ++kt) {
        #pragma unroll
        for (int nt = 0; nt < 4; ++nt) {
            #pragma unroll
            for (int j = 0; j < 8; ++j) {
                const float w = W[(kt * 32 + hi * 8 + j) * OUT_DIM + nt * 16 + lo];
                const unsigned short h = f2bf(w);
                Bh[kt][nt][j] = (short)h;
                Bl[kt][nt][j] = (short)f2bf(w - bf2f(h));
            }
        }
    }

    float aw_s[4], aw_t[4];
    #pragma unroll
    for (int nt = 0; nt < 4; ++nt) {
        aw_s[nt] = aw[nt * 16 + lo];
        aw_t[nt] = aw[OUT_DIM + nt * 16 + lo];
    }

    const int wave   = blockIdx.x * 4 + (threadIdx.x >> 6);
    const int nwaves = gridDim.x * 4;
    const int njobs  = (n + 15) >> 4;

    for (int job = wave; job < njobs; job += nwaves) {
        int r0 = job << 4;
        if (r0 + 16 > n) r0 = (n >= 16) ? (n - 16) : 0;   // overlap-tail, idempotent
        const float* frow = feat + (size_t)(r0 + lo) * IN_DIM + hi * 8;

        f32x4 acc[4] = {{0,0,0,0},{0,0,0,0},{0,0,0,0},{0,0,0,0}};

        #pragma unroll
        for (int kt = 0; kt < 4; ++kt) {
            const float4 a0 = *(const float4*)(frow + kt * 32);
            const float4 a1 = *(const float4*)(frow + kt * 32 + 4);
            const float av[8] = {a0.x, a0.y, a0.z, a0.w, a1.x, a1.y, a1.z, a1.w};
            short8 Ah, Al;
            #pragma unroll
            for (int j = 0; j < 8; ++j) {
                const unsigned short h = f2bf(av[j]);
                Ah[j] = (short)h;
                Al[j] = (short)f2bf(av[j] - bf2f(h));
            }
            #pragma unroll
            for (int nt = 0; nt < 4; ++nt) {
                acc[nt] = __builtin_amdgcn_mfma_f32_16x16x32_bf16(Ah, Bh[kt][nt], acc[nt], 0, 0, 0);
                acc[nt] = __builtin_amdgcn_mfma_f32_16x16x32_bf16(Ah, Bl[kt][nt], acc[nt], 0, 0, 0);
                acc[nt] = __builtin_amdgcn_mfma_f32_16x16x32_bf16(Al, Bh[kt][nt], acc[nt], 0, 0, 0);
            }
        }

        #pragma unroll
        for (int reg = 0; reg < 4; ++reg) {
            const int row = r0 + 4 * hi + reg;
            float sv = 0.f, tv = 0.f;
            #pragma unroll
            for (int nt = 0; nt < 4; ++nt) {
                const float v = acc[nt][reg];
                zb[(size_t)row * OUT_DIM + nt * 16 + lo] = f2bf(v);
                sv = fmaf(v, aw_s[nt], sv);
                tv = fmaf(v, aw_t[nt], tv);
            }
            #pragma unroll
            for (int off = 8; off > 0; off >>= 1) {
                sv += __shfl_xor(sv, off, 64);
                tv += __shfl_xor(tv, off, 64);
            }
            if (lo == 0) { s[row] = sv; t[row] = tv; }
        }
    }
}

// ---------------------------------------------------------------------------
// Kernel 2: TWO nodes per wave. Lanes 0..31 = node A, lanes 32..63 = node B.
// Lane l (within its half) owns dims {2l, 2l+1} of its node (ushort2 of zb row).
//   e_l     = leaky_relu(s[idx[node,l]] + t[node])     (all 64 lanes useful)
//   alpha_l = sum_k max(e_l - e_k, 0)                  (per-half __shfl bcast)
//   h[node, 2l..2l+1] = sum_k alpha_k * zb[idx_k][2l..2l+1]
// Per-node VMEM instrs ~17 (vs 35), per-node VALU ~1.5x lower, waves halved.
// ---------------------------------------------------------------------------
__global__ __launch_bounds__(256) void cgat_gather(
    const int*   __restrict__ idx,    // [n*32]
    const unsigned short* __restrict__ zb,  // [n*64] bf16
    const float* __restrict__ s,      // [n]
    const float* __restrict__ t,      // [n]
    float* __restrict__ h,            // [n*64]
    int n)
{
    const int lane = threadIdx.x & 63;
    const int l    = lane & 31;          // index within half
    const int hb   = lane & 32;          // half base (0 or 32) for shfl src

    int node = (blockIdx.x * 4 + (threadIdx.x >> 6)) * 2 + (lane >> 5);
    if (node >= n) node = n - 1;         // benign duplicate (identical values)

    const int   ij = idx[(size_t)node * DEG + l];   // two 128B segments per wave
    const float tn = t[node];

    float e = s[ij] + tn;                            // 64 random 4B lines / wave
    e = (e >= 0.f) ? e : NEG_SLOPE * e;

    // alpha_l = sum_k max(e_l - e_k, 0), per-half broadcast, 4 chains
    float al0 = 0.f, al1 = 0.f, al2 = 0.f, al3 = 0.f;
    #pragma unroll
    for (int k = 0; k < DEG; k += 4) {
        const float e0 = __shfl(e, hb | (k + 0), 64);
        const float e1 = __shfl(e, hb | (k + 1), 64);
        const float e2 = __shfl(e, hb | (k + 2), 64);
        const float e3 = __shfl(e, hb | (k + 3), 64);
        al0 += fmaxf(e - e0, 0.f);
        al1 += fmaxf(e - e1, 0.f);
        al2 += fmaxf(e - e2, 0.f);
        al3 += fmaxf(e - e3, 0.f);
    }
    const float alpha = (al0 + al1) + (al2 + al3);

    // h accumulation: lane owns 2 dims (one u32 = 2 bf16 of each gathered row)
    const unsigned* __restrict__ zw = (const unsigned*)zb;  // [n*32] u32
    float h0a = 0.f, h0b = 0.f, h1a = 0.f, h1b = 0.f;
    #pragma unroll
    for (int k = 0; k < DEG; k += 2) {
        const float a0 = __shfl(alpha, hb | (k + 0), 64);
        const int   i0 = __shfl(ij,    hb | (k + 0), 64);
        const float a1 = __shfl(alpha, hb | (k + 1), 64);
        const int   i1 = __shfl(ij,    hb | (k + 1), 64);
        const unsigned w0 = zw[(size_t)i0 * (OUT_DIM / 2) + l];  // 128B/half-wave
        const unsigned w1 = zw[(size_t)i1 * (OUT_DIM / 2) + l];
        h0a = fmaf(a0, __uint_as_float(w0 << 16), h0a);          // dim 2l
        h0b = fmaf(a0, __uint_as_float(w0 & 0xFFFF0000u), h0b);  // dim 2l+1
        h1a = fmaf(a1, __uint_as_float(w1 << 16), h1a);
        h1b = fmaf(a1, __uint_as_float(w1 & 0xFFFF0000u), h1b);
    }

    float2 out;
    out.x = h0a + h1a;
    out.y = h0b + h1b;
    *(float2*)(h + (size_t)node * OUT_DIM + 2 * l) = out;   // 256B/half coalesced
}

// ---------------------------------------------------------------------------
extern "C" void kernel_launch(void* const* d_in, const int* in_sizes, int n_in,
                              void* d_out, int out_size, void* d_ws, size_t ws_size,
                              hipStream_t stream)
{
    const float* feat = (const float*)d_in[0];   // [N,128] f32
    const int*   idx  = (const int*)  d_in[1];   // [N,32]  i32
    const float* W    = (const float*)d_in[2];   // [128,64] f32
    const float* aw   = (const float*)d_in[3];   // [128,1] f32
    float*       h    = (float*)d_out;           // [N,64] f32

    const int n = in_sizes[0] / IN_DIM;

    // workspace: s [n] f32, t [n] f32, zb [n*64] bf16 (all fully rewritten)
    float* s = (float*)d_ws;
    float* t = s + n;
    unsigned short* zb = (unsigned short*)(t + n);

    cgat_fc<<<512, 256, 0, stream>>>(feat, W, aw, zb, s, t, n);   // grid-stride

    const int ga_blocks = (n + 7) / 8;           // 4 waves/block, 2 nodes/wave
    cgat_gather<<<ga_blocks, 256, 0, stream>>>(idx, zb, s, t, h, n);
}